// Round 1
// 162.050 us; speedup vs baseline: 1.0288x; 1.0288x over previous
//
#include <hip/hip_runtime.h>
#include <stdint.h>

// Shapes (fixed by the reference)
#define B_ 8
#define N_ 1024
#define D_ 512
#define H_ 8
#define DH_ 64

// Round 9:
//  - All internal buffers bf16 -> f16 (xn, Wt, ht, oat); MFMA -> *_f16.
//    f16 has 10 mantissa bits vs bf16's 7: accuracy same-or-better.
//  - k_attn score pipeline in packed f16: Ed tables stored as packed f16
//    pairs; pm via v_pk_mul_f16/v_pk_max_f16 (3 ops / 2 elems vs 6), no
//    per-element f32->bf16 cvt. Adjacency mask via bit-spread trick:
//    t = ab|(ab<<15); mask_p = ((t>>2p)&0x10001)*0xFFFF.
//  - Register prefetch of next chunk AFTER the RAW barrier in k_gemm and
//    k_attn (hides L2 latency under the MFMA phase instead of exposing it).

using f16x8 = __attribute__((ext_vector_type(8))) _Float16;
using h2    = __attribute__((ext_vector_type(2))) _Float16;
using f32x4 = __attribute__((ext_vector_type(4))) float;

__device__ __forceinline__ float bf2f(uint32_t u) {
  union { uint32_t u; float f; } c; c.u = u << 16; return c.f;
}
__device__ __forceinline__ uint16_t f2bf(float f) {  // RNE (input-format writes only)
  union { float f; uint32_t u; } c; c.f = f;
  return (uint16_t)((c.u + 0x7FFFu + ((c.u >> 16) & 1u)) >> 16);
}
__device__ __forceinline__ uint16_t f2h(float f) {   // f32 -> f16 bits (1 cvt)
  union { _Float16 h; uint16_t u; } c; c.h = (_Float16)f; return c.u;
}
__device__ __forceinline__ float h2f(uint16_t u) {
  union { uint16_t u; _Float16 h; } c; c.u = u; return (float)c.h;
}
__device__ __forceinline__ uint32_t pk2h(float a, float b) {  // two f32 -> packed f16
  union { h2 h; uint32_t u; } c; c.h = (h2){(_Float16)a, (_Float16)b}; return c.u;
}
__device__ __forceinline__ h2 u2h2(uint32_t u) {
  union { uint32_t u; h2 h; } c; c.u = u; return c.h;
}
__device__ __forceinline__ uint32_t h22u(h2 h) {
  union { h2 h; uint32_t u; } c; c.h = h; return c.u;
}
__device__ __forceinline__ h2 h2splat(float v) {
  return (h2){(_Float16)v, (_Float16)v};
}
__device__ __forceinline__ h2 hmax2(h2 a, h2 b) {
#if defined(__has_builtin)
#if __has_builtin(__builtin_elementwise_max)
  return __builtin_elementwise_max(a, b);
#else
  h2 r; r.x = a.x > b.x ? a.x : b.x; r.y = a.y > b.y ? a.y : b.y; return r;
#endif
#else
  h2 r; r.x = a.x > b.x ? a.x : b.x; r.y = a.y > b.y ? a.y : b.y; return r;
#endif
}
__device__ __forceinline__ void load8f(const void* p, size_t idx, int f32, float v[8]) {
  if (f32) {
    const float4* q = (const float4*)((const float*)p + idx);
    float4 a = q[0], b = q[1];
    v[0]=a.x; v[1]=a.y; v[2]=a.z; v[3]=a.w; v[4]=b.x; v[5]=b.y; v[6]=b.z; v[7]=b.w;
  } else {
    uint4 u = *(const uint4*)((const uint16_t*)p + idx);
    const uint32_t* w = (const uint32_t*)&u;
#pragma unroll
    for (int e = 0; e < 4; e++) { v[2*e] = bf2f(w[e] & 0xffffu); v[2*e+1] = bf2f(w[e] >> 16); }
  }
}
__device__ __forceinline__ float load1f(const void* p, size_t idx, int f32) {
  return f32 ? ((const float*)p)[idx] : bf2f(((const uint16_t*)p)[idx]);
}

__device__ __forceinline__ int detect_f32_block(const uint16_t* x, int t, int* sflag) {
  if (t == 0) *sflag = 0;
  __syncthreads();
  uint2 u = ((const uint2*)x)[t];
  uint32_t bad = 0;
  bad |= (((u.x >> 7)  & 0xffu) >= 0x90u);
  bad |= (((u.x >> 23) & 0xffu) >= 0x90u);
  bad |= (((u.y >> 7)  & 0xffu) >= 0x90u);
  bad |= (((u.y >> 23) & 0xffu) >= 0x90u);
  if (__any(bad)) { if ((t & 63) == 0) atomicOr(sflag, 1); }
  __syncthreads();
  return *sflag;
}

// ---------------- k_pp: adj pack (0..2047) | detect->flag (2048) |
//                  LN1 (2049..4096) | W transpose (4097..4160)
__global__ __launch_bounds__(256) void k_pp(const int* __restrict__ adj,
                                            unsigned long long* __restrict__ adjp,
                                            const uint16_t* __restrict__ xr,
                                            int* __restrict__ flag,
                                            const void* __restrict__ x,
                                            const void* __restrict__ g,
                                            const void* __restrict__ bb,
                                            uint16_t* __restrict__ xn,
                                            const void* __restrict__ W,
                                            uint16_t* __restrict__ Wt) {
  const int bx = blockIdx.x, t = threadIdx.x;
  if (bx < 2048) {  // adjacency bit-pack
    const int row  = bx * 4 + (t >> 6);
    const int lane = t & 63;
    const int* ar = adj + (size_t)row * N_;
#pragma unroll
    for (int c = 0; c < 16; c++) {
      unsigned long long m = __ballot(ar[c * 64 + lane] > 0);
      if (lane == 0) adjp[(size_t)row * 16 + c] = m;
    }
    return;
  }
  __shared__ int sflag;
  if (bx == 2048) {
    int f32 = detect_f32_block(xr, t, &sflag);
    if (t == 0) *flag = f32;
    return;
  }
  if (bx >= 4097) {  // W [H][D][DH] -> Wt [H][DH][D] f16
    const int f32 = detect_f32_block(xr, t, &sflag);
    const int bw = bx - 4097;
    const int h = bw >> 3, dt = bw & 7;
    __shared__ uint16_t tile[64][65];
    const size_t sbase = ((size_t)h * D_ + dt * 64) * DH_;
    for (int e = t; e < 4096; e += 256) tile[e >> 6][e & 63] = f2h(load1f(W, sbase + e, f32));
    __syncthreads();
    uint16_t* dst = Wt + (size_t)h * DH_ * D_ + dt * 64;
    for (int e = t; e < 4096; e += 256) {
      const int k = e >> 6, dd = e & 63;
      dst[(size_t)k * D_ + dd] = tile[dd][k];
    }
    return;
  }
  // LayerNorm1 -> xn (f16)
  const int f32 = detect_f32_block(xr, t, &sflag);
  const int row  = (bx - 2049) * 4 + (t >> 6);
  const int lane = t & 63;
  const size_t base = (size_t)row * D_ + lane * 8;
  float v[8]; load8f(x, base, f32, v);
  float s = 0.f, sq = 0.f;
#pragma unroll
  for (int e = 0; e < 8; e++) { s += v[e]; sq += v[e] * v[e]; }
#pragma unroll
  for (int d = 32; d; d >>= 1) { s += __shfl_xor(s, d); sq += __shfl_xor(sq, d); }
  const float mean = s * (1.0f / D_);
  float var = fmaxf(sq * (1.0f / D_) - mean * mean, 0.0f);
  const float inv = 1.0f / (sqrtf(var) + 1e-6f);
  float gv[8], bv[8];
  load8f(g, lane * 8, f32, gv); load8f(bb, lane * 8, f32, bv);
  uint4 ov; uint32_t* ow = (uint32_t*)&ov;
#pragma unroll
  for (int e = 0; e < 4; e++) {
    float o0 = gv[2*e]   * ((v[2*e]   - mean) * inv) + bv[2*e];
    float o1 = gv[2*e+1] * ((v[2*e+1] - mean) * inv) + bv[2*e+1];
    ow[e] = (uint32_t)f2h(o0) | ((uint32_t)f2h(o1) << 16);
  }
  *(uint4*)(xn + base) = ov;
}

// ---------------- h = xn @ W per head -> ht[bh][dh][n] f16, + fs/fd epilogue
// BK=64: 8 K-iters, 16 barriers, 8 MFMA per barrier-pair per wave.
// Prefetch: next K-tile loaded into regs right after RAW barrier (hides L2).
__global__ __launch_bounds__(256, 2) void k_gemm(const uint16_t* __restrict__ xn,
                                              const uint16_t* __restrict__ Wt,
                                              uint16_t* __restrict__ ht,
                                              const void* __restrict__ asr,
                                              const void* __restrict__ adst,
                                              float* __restrict__ fs,
                                              float* __restrict__ fd,
                                              const int* __restrict__ flag) {
  const int h = blockIdx.x;
  const int r0 = blockIdx.y * 64;
  const int t = threadIdx.x;
  const int wv = t >> 6, lane = t & 63, q = lane >> 4, m16 = lane & 15;
  const int wr = wv >> 1, wc = wv & 1;

  __shared__ union {
    struct { __align__(16) uint16_t A[64 * 72]; __align__(16) uint16_t Bt[64 * 72]; } st;
    __align__(16) uint16_t tr[64 * 72];  // [dh][seq] transpose buffer
  } L;

  f32x4 acc[2][2] = {};
  const int srow = t >> 2, soff = (t & 3) * 16;
  const uint16_t* gA = xn + (size_t)(r0 + srow) * D_ + soff;
  const uint16_t* gB = Wt + ((size_t)h * DH_ + srow) * D_ + soff;
  uint16_t* lA = &L.st.A[srow * 72 + soff];
  uint16_t* lB = &L.st.Bt[srow * 72 + soff];

  uint4 va0 = *(const uint4*)(gA);
  uint4 va1 = *(const uint4*)(gA + 8);
  uint4 vb0 = *(const uint4*)(gB);
  uint4 vb1 = *(const uint4*)(gB + 8);
  for (int k0 = 0; k0 < D_; k0 += 64) {
    __syncthreads();               // WAR
    *(uint4*)lA = va0;  *(uint4*)(lA + 8) = va1;
    *(uint4*)lB = vb0;  *(uint4*)(lB + 8) = vb1;
    __syncthreads();               // RAW
    if (k0 + 64 < D_) {            // prefetch next tile (overlaps MFMA below)
      va0 = *(const uint4*)(gA + k0 + 64);
      va1 = *(const uint4*)(gA + k0 + 72);
      vb0 = *(const uint4*)(gB + k0 + 64);
      vb1 = *(const uint4*)(gB + k0 + 72);
    }
#pragma unroll
    for (int ks = 0; ks < 2; ks++) {
      f16x8 a0 = *(const f16x8*)&L.st.A[(wr * 32 + m16) * 72 + ks * 32 + q * 8];
      f16x8 a1 = *(const f16x8*)&L.st.A[(wr * 32 + 16 + m16) * 72 + ks * 32 + q * 8];
      f16x8 b0 = *(const f16x8*)&L.st.Bt[(wc * 32 + m16) * 72 + ks * 32 + q * 8];
      f16x8 b1 = *(const f16x8*)&L.st.Bt[(wc * 32 + 16 + m16) * 72 + ks * 32 + q * 8];
      acc[0][0] = __builtin_amdgcn_mfma_f32_16x16x32_f16(a0, b0, acc[0][0], 0, 0, 0);
      acc[0][1] = __builtin_amdgcn_mfma_f32_16x16x32_f16(a0, b1, acc[0][1], 0, 0, 0);
      acc[1][0] = __builtin_amdgcn_mfma_f32_16x16x32_f16(a1, b0, acc[1][0], 0, 0, 0);
      acc[1][1] = __builtin_amdgcn_mfma_f32_16x16x32_f16(a1, b1, acc[1][1], 0, 0, 0);
    }
  }
  __syncthreads();
#pragma unroll
  for (int i2 = 0; i2 < 2; i2++)
#pragma unroll
    for (int j2 = 0; j2 < 2; j2++) {
      f32x4 vv = acc[i2][j2];
      const int sl = wr * 32 + i2 * 16 + q * 4;   // seq-local
      const int kl = wc * 32 + j2 * 16 + m16;     // dh-local
#pragma unroll
      for (int r = 0; r < 4; r++) L.tr[kl * 72 + sl + r] = f2h(vv[r]);
    }
  __syncthreads();
  const int b = r0 >> 10, n0 = r0 & 1023;
  {
    const int k = t >> 2, ns = (t & 3) * 16;
    const size_t base = (((size_t)b * H_ + h) * DH_ + k) * (size_t)N_ + n0 + ns;
    *(uint4*)(ht + base) = *(const uint4*)&L.tr[k * 72 + ns];
    *(uint4*)(ht + base + 8) = *(const uint4*)&L.tr[k * 72 + ns + 8];
  }
  {  // fused fs/fd
    const int f32 = *flag;
    const int nl = t >> 2, qd = (t & 3) * 16;
    float ss = 0.f, sd = 0.f;
#pragma unroll
    for (int dd = 0; dd < 16; dd++) {
      float hv = h2f(L.tr[(qd + dd) * 72 + nl]);
      ss = fmaf(hv, load1f(asr,  h * DH_ + qd + dd, f32), ss);
      sd = fmaf(hv, load1f(adst, h * DH_ + qd + dd, f32), sd);
    }
    ss += __shfl_xor(ss, 1); ss += __shfl_xor(ss, 2);
    sd += __shfl_xor(sd, 1); sd += __shfl_xor(sd, 2);
    if ((t & 3) == 0) {
      fs[((size_t)b * H_ + h) * N_ + n0 + nl] = ss;
      fd[((size_t)b * H_ + h) * N_ + n0 + nl] = sd;
    }
  }
}

// ---------------- attention v4: out[i,dh] = (1/l_i) sum_j p_ij h[j,dh]
// grid 512: bh = bid&63 (XCD = bh%8), itile = bid>>6 (128-i tile).
// f16 packed score pipeline: Ed tables as packed f16 pairs, pm via
// v_pk_mul/v_pk_max, adjacency mask via bit-spread (ab|(ab<<15)).
// Register prefetch of next chunk after the RAW barrier.
__global__ __launch_bounds__(256, 2) void k_attn(const uint16_t* __restrict__ ht,
                                                 const float* __restrict__ fs,
                                                 const float* __restrict__ fd,
                                                 const uint32_t* __restrict__ adjp,
                                                 uint16_t* __restrict__ oat) {
  const int bid = blockIdx.x;
  const int bh = bid & 63, itile = bid >> 6;
  const int b = bh >> 3, h = bh & 7;
  const int i0 = itile * 128;
  const int t = threadIdx.x, wv = t >> 6, lane = t & 63, q = lane >> 4, m16 = lane & 15;
  __shared__ __align__(16) uint16_t Hs[64 * 136];  // 17 KB f16 chunk, stride 136
  __shared__ __align__(16) uint32_t E1p[N_ / 2];   // 2 KB packed f16 (e^{fd_j} pairs)
  __shared__ __align__(16) uint32_t E2p[N_ / 2];   // 2 KB packed f16 (e^{0.2 fd_j})
  for (int jp = t; jp < N_ / 2; jp += 256) {
    float2 fv = ((const float2*)(fd + (size_t)bh * N_))[jp];
    E1p[jp] = pk2h(exp2f(fv.x * 1.44269504f), exp2f(fv.y * 1.44269504f));
    E2p[jp] = pk2h(exp2f(fv.x * 0.28853901f), exp2f(fv.y * 0.28853901f));
  }
  const int iA0 = i0 + wv * 32 + m16;
  const int iA1 = iA0 + 16;
  const float fs0 = fs[(size_t)bh * N_ + iA0];
  const float fs1 = fs[(size_t)bh * N_ + iA1];
  const h2 Ea0 = h2splat(exp2f(fs0 * 1.44269504f));
  const h2 Eb0 = h2splat(exp2f(fs0 * 0.28853901f));
  const h2 Ea1 = h2splat(exp2f(fs1 * 1.44269504f));
  const h2 Eb1 = h2splat(exp2f(fs1 * 0.28853901f));
  const uint32_t* arow0 = adjp + ((size_t)b * N_ + iA0) * 32;
  const uint32_t* arow1 = adjp + ((size_t)b * N_ + iA1) * 32;
  const uint16_t* gH = ht + (size_t)bh * (DH_ * N_) + (size_t)(t >> 2) * N_ + (t & 3) * 32;
  uint16_t* lH = &Hs[(t >> 2) * 136 + (t & 3) * 32];
  union { uint16_t u[8]; f16x8 v; } ones;
#pragma unroll
  for (int e = 0; e < 8; e++) ones.u[e] = 0x3C00u;  // 1.0 f16
  f32x4 acc[2][5] = {};
  uint4 v0 = *(const uint4*)(gH);
  uint4 v1 = *(const uint4*)(gH + 8);
  uint4 v2 = *(const uint4*)(gH + 16);
  uint4 v3 = *(const uint4*)(gH + 24);
  uint4 aw0 = *(const uint4*)(arow0);
  uint4 aw1 = *(const uint4*)(arow1);
  for (int c = 0; c < 8; c++) {
    __syncthreads();               // WAR (+ c==0: E tables ready)
    *(uint4*)(lH)      = v0;
    *(uint4*)(lH + 8)  = v1;
    *(uint4*)(lH + 16) = v2;
    *(uint4*)(lH + 24) = v3;
    __syncthreads();               // RAW
    const uint32_t cw0[4] = {aw0.x, aw0.y, aw0.z, aw0.w};
    const uint32_t cw1[4] = {aw1.x, aw1.y, aw1.z, aw1.w};
    if (c < 7) {                   // prefetch next chunk under this chunk's MFMA
      const int jn = (c + 1) * 128;
      v0 = *(const uint4*)(gH + jn);
      v1 = *(const uint4*)(gH + jn + 8);
      v2 = *(const uint4*)(gH + jn + 16);
      v3 = *(const uint4*)(gH + jn + 24);
      aw0 = *(const uint4*)(arow0 + (c + 1) * 4);
      aw1 = *(const uint4*)(arow1 + (c + 1) * 4);
    }
    const int eb = c * 64;
#pragma unroll
    for (int s = 0; s < 4; s++) {
      const int js = s * 32;
      f16x8 hf0 = *(const f16x8*)&Hs[(m16)      * 136 + js + q * 8];
      f16x8 hf1 = *(const f16x8*)&Hs[(16 + m16) * 136 + js + q * 8];
      f16x8 hf2 = *(const f16x8*)&Hs[(32 + m16) * 136 + js + q * 8];
      f16x8 hf3 = *(const f16x8*)&Hs[(48 + m16) * 136 + js + q * 8];
      const int ei = eb + s * 16 + q * 4;
      const uint4 e1u = *(const uint4*)&E1p[ei];
      const uint4 e2u = *(const uint4*)&E2p[ei];
      const h2 e1[4] = {u2h2(e1u.x), u2h2(e1u.y), u2h2(e1u.z), u2h2(e1u.w)};
      const h2 e2[4] = {u2h2(e2u.x), u2h2(e2u.y), u2h2(e2u.z), u2h2(e2u.w)};
      const uint32_t ab0 = (cw0[s] >> (q * 8)) & 0xffu;
      const uint32_t ab1 = (cw1[s] >> (q * 8)) & 0xffu;
      const uint32_t t0 = ab0 | (ab0 << 15);   // bit 2p @pos2p, bit 2p+1 @pos 2p+16
      const uint32_t t1 = ab1 | (ab1 << 15);
#pragma unroll
      for (int f = 0; f < 2; f++) {
        const h2 Ea = f ? Ea1 : Ea0;
        const h2 Eb = f ? Eb1 : Eb0;
        const uint32_t tt = f ? t1 : t0;
        union { uint32_t u[4]; f16x8 v; } af;
#pragma unroll
        for (int p = 0; p < 4; p++) {
          h2 pm = hmax2(Ea * e1[p], Eb * e2[p]);
          af.u[p] = h22u(pm) & (((tt >> (2 * p)) & 0x10001u) * 0xFFFFu);
        }
        acc[f][0] = __builtin_amdgcn_mfma_f32_16x16x32_f16(af.v, hf0, acc[f][0], 0, 0, 0);
        acc[f][1] = __builtin_amdgcn_mfma_f32_16x16x32_f16(af.v, hf1, acc[f][1], 0, 0, 0);
        acc[f][2] = __builtin_amdgcn_mfma_f32_16x16x32_f16(af.v, hf2, acc[f][2], 0, 0, 0);
        acc[f][3] = __builtin_amdgcn_mfma_f32_16x16x32_f16(af.v, hf3, acc[f][3], 0, 0, 0);
        acc[f][4] = __builtin_amdgcn_mfma_f32_16x16x32_f16(af.v, ones.v, acc[f][4], 0, 0, 0);
      }
    }
  }
#pragma unroll
  for (int f = 0; f < 2; f++) {
    float linv[4];
#pragma unroll
    for (int r = 0; r < 4; r++) linv[r] = 1.0f / acc[f][4][r];
    const int ibl = i0 + wv * 32 + f * 16 + q * 4;
#pragma unroll
    for (int nt = 0; nt < 4; nt++)
#pragma unroll
      for (int r = 0; r < 4; r++) {
        oat[((size_t)b * N_ + ibl + r) * D_ + h * DH_ + nt * 16 + m16] =
            f2h(acc[f][nt][r] * linv[r]);
      }
  }
}

// ---------------- final: y = LN2(x + elu(oat)); output dtype matches input
__global__ __launch_bounds__(256) void k_final(const void* __restrict__ x,
                                               const uint16_t* __restrict__ oa,
                                               const void* __restrict__ g,
                                               const void* __restrict__ bb,
                                               void* __restrict__ out,
                                               const int* __restrict__ flag) {
  const int f32 = *flag;
  const int row = blockIdx.x * 4 + (threadIdx.x >> 6);
  const int lane = threadIdx.x & 63;
  const size_t base = (size_t)row * D_ + lane * 8;
  float xv[8]; load8f(x, base, f32, xv);
  uint4 av = *(const uint4*)(oa + base);
  const uint32_t* aw = (const uint32_t*)&av;
  float v[8], s = 0.f, sq = 0.f;
#pragma unroll
  for (int e = 0; e < 4; e++) {
    float a0 = h2f((uint16_t)(aw[e] & 0xffffu));
    float a1 = h2f((uint16_t)(aw[e] >> 16));
    a0 = a0 > 0.f ? a0 : exp2f(a0 * 1.44269504f) - 1.0f;
    a1 = a1 > 0.f ? a1 : exp2f(a1 * 1.44269504f) - 1.0f;
    float t0 = xv[2*e] + a0, t1 = xv[2*e+1] + a1;
    v[2*e] = t0; v[2*e+1] = t1;
    s += t0 + t1; sq += t0 * t0 + t1 * t1;
  }
#pragma unroll
  for (int d = 32; d; d >>= 1) { s += __shfl_xor(s, d); sq += __shfl_xor(sq, d); }
  const float mean = s * (1.0f / D_);
  float var = fmaxf(sq * (1.0f / D_) - mean * mean, 0.0f);
  const float inv = 1.0f / (sqrtf(var) + 1e-6f);
  float gv[8], bv[8];
  load8f(g, lane * 8, f32, gv); load8f(bb, lane * 8, f32, bv);
  float r8[8];
#pragma unroll
  for (int e = 0; e < 8; e++) r8[e] = gv[e] * ((v[e] - mean) * inv) + bv[e];
  if (f32) {
    float* o = (float*)out + base;
    float4 o0 = {r8[0], r8[1], r8[2], r8[3]};
    float4 o1 = {r8[4], r8[5], r8[6], r8[7]};
    *(float4*)(o) = o0;
    *(float4*)(o + 4) = o1;
  } else {
    uint4 ov; uint32_t* ow = (uint32_t*)&ov;
#pragma unroll
    for (int e = 0; e < 4; e++)
      ow[e] = (uint32_t)f2bf(r8[2*e]) | ((uint32_t)f2bf(r8[2*e+1]) << 16);
    *(uint4*)((uint16_t*)out + base) = ov;
  }
}

extern "C" void kernel_launch(void* const* d_in, const int* in_sizes, int n_in,
                              void* d_out, int out_size, void* d_ws, size_t ws_size,
                              hipStream_t stream) {
  const void* x = d_in[0];
  // d_in[1] = mask (unused)
  const int* adj = (const int*)d_in[2];
  const void* W = d_in[3];
  const void* asr = d_in[4];
  const void* adst = d_in[5];
  const void* g1 = d_in[6];
  const void* b1 = d_in[7];
  const void* g2 = d_in[8];
  const void* b2 = d_in[9];

  uint8_t* ws = (uint8_t*)d_ws;
  uint16_t* ht = (uint16_t*)(ws);                // 8 MB  [bh][dh][n] f16
  uint16_t* xn = (uint16_t*)(ws + 8388608);      // 8 MB  (reused as oat)
  uint16_t* oat = xn;
  uint16_t* Wt = (uint16_t*)(ws + 16777216);     // 512 KB
  uint32_t* adjp = (uint32_t*)(ws + 17301504);   // 1 MB
  float* fs = (float*)(ws + 18350080);           // 256 KB
  float* fd = (float*)(ws + 18612224);           // 256 KB
  int* flag = (int*)(ws + 18874368);             // 4 B dtype flag

  k_pp<<<dim3(4161), dim3(256), 0, stream>>>(adj, (unsigned long long*)adjp,
                                             (const uint16_t*)x, flag,
                                             x, g1, b1, xn, W, Wt);
  k_gemm<<<dim3(8, 128), dim3(256), 0, stream>>>(xn, Wt, ht, asr, adst, fs, fd, flag);
  k_attn<<<dim3(512), dim3(256), 0, stream>>>(ht, fs, fd, adjp, oat);
  k_final<<<dim3(2048), dim3(256), 0, stream>>>(x, oat, g2, b2, d_out, flag);
}

// Round 2
// 157.563 us; speedup vs baseline: 1.0581x; 1.0285x over previous
//
#include <hip/hip_runtime.h>
#include <stdint.h>

// Shapes (fixed by the reference)
#define B_ 8
#define N_ 1024
#define D_ 512
#define H_ 8
#define DH_ 64

// Round 10:
//  - k_attn: H staging via global_load_lds (async, no reg round-trip, no
//    ds_write) into linear [64][128] LDS with XOR swizzle (elem ^ (row&7)<<3)
//    applied on the *global source* (write side) and on ds_read (read side).
//    Double-buffered Hs[2] -> ONE barrier per chunk (was 2); loads for c+1
//    issue right after the barrier and drain at the next barrier's implicit
//    vmcnt(0) (full compute phase of latency hiding).
//  - k_attn: row-scale invariance: out_i = sum p h / sum p is invariant to
//    scaling row i, so Es/Es2 factors are dropped; p' = max(e1, R_i*e2) with
//    R_i = e^{-0.8 fs_i}. One pk_mul saved per pair, no Es exp2 setup.
//  - k_gemm: double-buffered A/B LDS, ONE barrier per K-iter (was 2);
//    ds_writes of tile k+1 overlap MFMA of tile k.

using f16x8 = __attribute__((ext_vector_type(8))) _Float16;
using h2    = __attribute__((ext_vector_type(2))) _Float16;
using f32x4 = __attribute__((ext_vector_type(4))) float;

__device__ __forceinline__ float bf2f(uint32_t u) {
  union { uint32_t u; float f; } c; c.u = u << 16; return c.f;
}
__device__ __forceinline__ uint16_t f2bf(float f) {  // RNE (input-format writes only)
  union { float f; uint32_t u; } c; c.f = f;
  return (uint16_t)((c.u + 0x7FFFu + ((c.u >> 16) & 1u)) >> 16);
}
__device__ __forceinline__ uint16_t f2h(float f) {   // f32 -> f16 bits (1 cvt)
  union { _Float16 h; uint16_t u; } c; c.h = (_Float16)f; return c.u;
}
__device__ __forceinline__ float h2f(uint16_t u) {
  union { uint16_t u; _Float16 h; } c; c.u = u; return (float)c.h;
}
__device__ __forceinline__ uint32_t pk2h(float a, float b) {  // two f32 -> packed f16
  union { h2 h; uint32_t u; } c; c.h = (h2){(_Float16)a, (_Float16)b}; return c.u;
}
__device__ __forceinline__ h2 u2h2(uint32_t u) {
  union { uint32_t u; h2 h; } c; c.u = u; return c.h;
}
__device__ __forceinline__ uint32_t h22u(h2 h) {
  union { h2 h; uint32_t u; } c; c.h = h; return c.u;
}
__device__ __forceinline__ h2 h2splat(float v) {
  return (h2){(_Float16)v, (_Float16)v};
}
__device__ __forceinline__ h2 hmax2(h2 a, h2 b) {
#if defined(__has_builtin)
#if __has_builtin(__builtin_elementwise_max)
  return __builtin_elementwise_max(a, b);
#else
  h2 r; r.x = a.x > b.x ? a.x : b.x; r.y = a.y > b.y ? a.y : b.y; return r;
#endif
#else
  h2 r; r.x = a.x > b.x ? a.x : b.x; r.y = a.y > b.y ? a.y : b.y; return r;
#endif
}
__device__ __forceinline__ void gload16(const void* g, void* l) {
  __builtin_amdgcn_global_load_lds(
      (const __attribute__((address_space(1))) uint32_t*)g,
      (__attribute__((address_space(3))) uint32_t*)l, 16, 0, 0);
}
__device__ __forceinline__ void load8f(const void* p, size_t idx, int f32, float v[8]) {
  if (f32) {
    const float4* q = (const float4*)((const float*)p + idx);
    float4 a = q[0], b = q[1];
    v[0]=a.x; v[1]=a.y; v[2]=a.z; v[3]=a.w; v[4]=b.x; v[5]=b.y; v[6]=b.z; v[7]=b.w;
  } else {
    uint4 u = *(const uint4*)((const uint16_t*)p + idx);
    const uint32_t* w = (const uint32_t*)&u;
#pragma unroll
    for (int e = 0; e < 4; e++) { v[2*e] = bf2f(w[e] & 0xffffu); v[2*e+1] = bf2f(w[e] >> 16); }
  }
}
__device__ __forceinline__ float load1f(const void* p, size_t idx, int f32) {
  return f32 ? ((const float*)p)[idx] : bf2f(((const uint16_t*)p)[idx]);
}

__device__ __forceinline__ int detect_f32_block(const uint16_t* x, int t, int* sflag) {
  if (t == 0) *sflag = 0;
  __syncthreads();
  uint2 u = ((const uint2*)x)[t];
  uint32_t bad = 0;
  bad |= (((u.x >> 7)  & 0xffu) >= 0x90u);
  bad |= (((u.x >> 23) & 0xffu) >= 0x90u);
  bad |= (((u.y >> 7)  & 0xffu) >= 0x90u);
  bad |= (((u.y >> 23) & 0xffu) >= 0x90u);
  if (__any(bad)) { if ((t & 63) == 0) atomicOr(sflag, 1); }
  __syncthreads();
  return *sflag;
}

// ---------------- k_pp: adj pack (0..2047) | detect->flag (2048) |
//                  LN1 (2049..4096) | W transpose (4097..4160)
__global__ __launch_bounds__(256) void k_pp(const int* __restrict__ adj,
                                            unsigned long long* __restrict__ adjp,
                                            const uint16_t* __restrict__ xr,
                                            int* __restrict__ flag,
                                            const void* __restrict__ x,
                                            const void* __restrict__ g,
                                            const void* __restrict__ bb,
                                            uint16_t* __restrict__ xn,
                                            const void* __restrict__ W,
                                            uint16_t* __restrict__ Wt) {
  const int bx = blockIdx.x, t = threadIdx.x;
  if (bx < 2048) {  // adjacency bit-pack
    const int row  = bx * 4 + (t >> 6);
    const int lane = t & 63;
    const int* ar = adj + (size_t)row * N_;
#pragma unroll
    for (int c = 0; c < 16; c++) {
      unsigned long long m = __ballot(ar[c * 64 + lane] > 0);
      if (lane == 0) adjp[(size_t)row * 16 + c] = m;
    }
    return;
  }
  __shared__ int sflag;
  if (bx == 2048) {
    int f32 = detect_f32_block(xr, t, &sflag);
    if (t == 0) *flag = f32;
    return;
  }
  if (bx >= 4097) {  // W [H][D][DH] -> Wt [H][DH][D] f16
    const int f32 = detect_f32_block(xr, t, &sflag);
    const int bw = bx - 4097;
    const int h = bw >> 3, dt = bw & 7;
    __shared__ uint16_t tile[64][65];
    const size_t sbase = ((size_t)h * D_ + dt * 64) * DH_;
    for (int e = t; e < 4096; e += 256) tile[e >> 6][e & 63] = f2h(load1f(W, sbase + e, f32));
    __syncthreads();
    uint16_t* dst = Wt + (size_t)h * DH_ * D_ + dt * 64;
    for (int e = t; e < 4096; e += 256) {
      const int k = e >> 6, dd = e & 63;
      dst[(size_t)k * D_ + dd] = tile[dd][k];
    }
    return;
  }
  // LayerNorm1 -> xn (f16)
  const int f32 = detect_f32_block(xr, t, &sflag);
  const int row  = (bx - 2049) * 4 + (t >> 6);
  const int lane = t & 63;
  const size_t base = (size_t)row * D_ + lane * 8;
  float v[8]; load8f(x, base, f32, v);
  float s = 0.f, sq = 0.f;
#pragma unroll
  for (int e = 0; e < 8; e++) { s += v[e]; sq += v[e] * v[e]; }
#pragma unroll
  for (int d = 32; d; d >>= 1) { s += __shfl_xor(s, d); sq += __shfl_xor(sq, d); }
  const float mean = s * (1.0f / D_);
  float var = fmaxf(sq * (1.0f / D_) - mean * mean, 0.0f);
  const float inv = 1.0f / (sqrtf(var) + 1e-6f);
  float gv[8], bv[8];
  load8f(g, lane * 8, f32, gv); load8f(bb, lane * 8, f32, bv);
  uint4 ov; uint32_t* ow = (uint32_t*)&ov;
#pragma unroll
  for (int e = 0; e < 4; e++) {
    float o0 = gv[2*e]   * ((v[2*e]   - mean) * inv) + bv[2*e];
    float o1 = gv[2*e+1] * ((v[2*e+1] - mean) * inv) + bv[2*e+1];
    ow[e] = (uint32_t)f2h(o0) | ((uint32_t)f2h(o1) << 16);
  }
  *(uint4*)(xn + base) = ov;
}

// ---------------- h = xn @ W per head -> ht[bh][dh][n] f16, + fs/fd epilogue
// BK=64, double-buffered LDS: ONE barrier per K-iter; ds_writes of tile k+1
// overlap the MFMAs of tile k; global loads for k+2 issued under compute.
__global__ __launch_bounds__(256, 2) void k_gemm(const uint16_t* __restrict__ xn,
                                              const uint16_t* __restrict__ Wt,
                                              uint16_t* __restrict__ ht,
                                              const void* __restrict__ asr,
                                              const void* __restrict__ adst,
                                              float* __restrict__ fs,
                                              float* __restrict__ fd,
                                              const int* __restrict__ flag) {
  const int h = blockIdx.x;
  const int r0 = blockIdx.y * 64;
  const int t = threadIdx.x;
  const int wv = t >> 6, lane = t & 63, q = lane >> 4, m16 = lane & 15;
  const int wr = wv >> 1, wc = wv & 1;

  __shared__ union {
    struct { __align__(16) uint16_t A[2][64 * 72]; __align__(16) uint16_t Bt[2][64 * 72]; } st;
    __align__(16) uint16_t tr[64 * 72];  // [dh][seq] transpose buffer
  } L;

  f32x4 acc[2][2] = {};
  const int srow = t >> 2, soff = (t & 3) * 16;
  const int o = srow * 72 + soff;
  const uint16_t* gA = xn + (size_t)(r0 + srow) * D_ + soff;
  const uint16_t* gB = Wt + ((size_t)h * DH_ + srow) * D_ + soff;

  uint4 va0 = *(const uint4*)(gA);
  uint4 va1 = *(const uint4*)(gA + 8);
  uint4 vb0 = *(const uint4*)(gB);
  uint4 vb1 = *(const uint4*)(gB + 8);
  *(uint4*)&L.st.A[0][o]      = va0;  *(uint4*)&L.st.A[0][o + 8]  = va1;
  *(uint4*)&L.st.Bt[0][o]     = vb0;  *(uint4*)&L.st.Bt[0][o + 8] = vb1;
  va0 = *(const uint4*)(gA + 64);  va1 = *(const uint4*)(gA + 72);
  vb0 = *(const uint4*)(gB + 64);  vb1 = *(const uint4*)(gB + 72);
  int cur = 0;
  for (int k0 = 0; k0 < D_; k0 += 64) {
    __syncthreads();   // buf[cur] writes visible; buf[cur^1] reads (prev iter) done
    if (k0 + 64 < D_) {
      *(uint4*)&L.st.A[cur ^ 1][o]      = va0;  *(uint4*)&L.st.A[cur ^ 1][o + 8]  = va1;
      *(uint4*)&L.st.Bt[cur ^ 1][o]     = vb0;  *(uint4*)&L.st.Bt[cur ^ 1][o + 8] = vb1;
      if (k0 + 128 < D_) {
        va0 = *(const uint4*)(gA + k0 + 128);  va1 = *(const uint4*)(gA + k0 + 136);
        vb0 = *(const uint4*)(gB + k0 + 128);  vb1 = *(const uint4*)(gB + k0 + 136);
      }
    }
#pragma unroll
    for (int ks = 0; ks < 2; ks++) {
      f16x8 a0 = *(const f16x8*)&L.st.A[cur][(wr * 32 + m16) * 72 + ks * 32 + q * 8];
      f16x8 a1 = *(const f16x8*)&L.st.A[cur][(wr * 32 + 16 + m16) * 72 + ks * 32 + q * 8];
      f16x8 b0 = *(const f16x8*)&L.st.Bt[cur][(wc * 32 + m16) * 72 + ks * 32 + q * 8];
      f16x8 b1 = *(const f16x8*)&L.st.Bt[cur][(wc * 32 + 16 + m16) * 72 + ks * 32 + q * 8];
      acc[0][0] = __builtin_amdgcn_mfma_f32_16x16x32_f16(a0, b0, acc[0][0], 0, 0, 0);
      acc[0][1] = __builtin_amdgcn_mfma_f32_16x16x32_f16(a0, b1, acc[0][1], 0, 0, 0);
      acc[1][0] = __builtin_amdgcn_mfma_f32_16x16x32_f16(a1, b0, acc[1][0], 0, 0, 0);
      acc[1][1] = __builtin_amdgcn_mfma_f32_16x16x32_f16(a1, b1, acc[1][1], 0, 0, 0);
    }
    cur ^= 1;
  }
  __syncthreads();
#pragma unroll
  for (int i2 = 0; i2 < 2; i2++)
#pragma unroll
    for (int j2 = 0; j2 < 2; j2++) {
      f32x4 vv = acc[i2][j2];
      const int sl = wr * 32 + i2 * 16 + q * 4;   // seq-local
      const int kl = wc * 32 + j2 * 16 + m16;     // dh-local
#pragma unroll
      for (int r = 0; r < 4; r++) L.tr[kl * 72 + sl + r] = f2h(vv[r]);
    }
  __syncthreads();
  const int b = r0 >> 10, n0 = r0 & 1023;
  {
    const int k = t >> 2, ns = (t & 3) * 16;
    const size_t base = (((size_t)b * H_ + h) * DH_ + k) * (size_t)N_ + n0 + ns;
    *(uint4*)(ht + base) = *(const uint4*)&L.tr[k * 72 + ns];
    *(uint4*)(ht + base + 8) = *(const uint4*)&L.tr[k * 72 + ns + 8];
  }
  {  // fused fs/fd
    const int f32 = *flag;
    const int nl = t >> 2, qd = (t & 3) * 16;
    float ss = 0.f, sd = 0.f;
#pragma unroll
    for (int dd = 0; dd < 16; dd++) {
      float hv = h2f(L.tr[(qd + dd) * 72 + nl]);
      ss = fmaf(hv, load1f(asr,  h * DH_ + qd + dd, f32), ss);
      sd = fmaf(hv, load1f(adst, h * DH_ + qd + dd, f32), sd);
    }
    ss += __shfl_xor(ss, 1); ss += __shfl_xor(ss, 2);
    sd += __shfl_xor(sd, 1); sd += __shfl_xor(sd, 2);
    if ((t & 3) == 0) {
      fs[((size_t)b * H_ + h) * N_ + n0 + nl] = ss;
      fd[((size_t)b * H_ + h) * N_ + n0 + nl] = sd;
    }
  }
}

// ---------------- attention v5: out[i,dh] = (1/l_i) sum_j p_ij h[j,dh]
// grid 512: bh = bid&63 (XCD = bh%8), itile = bid>>6 (128-i tile).
// Async H staging: global_load_lds into Hs[2] (linear [64][128], XOR-swizzled
// source: elem ^ ((row&7)<<3)); ONE barrier per chunk. Row-scale-invariant
// scores: p' = max(e^{fd_j}, R_i * e^{0.2 fd_j}), R_i = e^{-0.8 fs_i}.
__global__ __launch_bounds__(256, 2) void k_attn(const uint16_t* __restrict__ ht,
                                                 const float* __restrict__ fs,
                                                 const float* __restrict__ fd,
                                                 const uint32_t* __restrict__ adjp,
                                                 uint16_t* __restrict__ oat) {
  const int bid = blockIdx.x;
  const int bh = bid & 63, itile = bid >> 6;
  const int b = bh >> 3, h = bh & 7;
  const int i0 = itile * 128;
  const int t = threadIdx.x, wv = t >> 6, lane = t & 63, q = lane >> 4, m16 = lane & 15;
  __shared__ __align__(16) uint16_t Hs[2][64 * 128];  // 32 KB dbuf, swizzled
  __shared__ __align__(16) uint32_t E1p[N_ / 2];      // 2 KB packed f16 e^{fd}
  __shared__ __align__(16) uint32_t E2p[N_ / 2];      // 2 KB packed f16 e^{0.2 fd}

  const uint16_t* hbase = ht + (size_t)bh * (DH_ * N_);
  int srow[4], soff[4];
#pragma unroll
  for (int i = 0; i < 4; i++) {
    const int r = wv * 16 + i * 4 + (lane >> 4);
    srow[i] = r;
    soff[i] = ((lane & 15) * 8) ^ ((r & 7) << 3);   // elements (16B granular)
  }
#define STAGE(jc, buf)                                                         \
  {                                                                            \
    _Pragma("unroll")                                                          \
    for (int ii = 0; ii < 4; ii++) {                                           \
      gload16(hbase + (size_t)srow[ii] * N_ + (jc) + soff[ii],                 \
              &(buf)[(wv * 16 + ii * 4) * 128]);                               \
    }                                                                          \
  }
  STAGE(0, Hs[0]);   // async: lands by the first barrier's vmcnt drain

  for (int jp = t; jp < N_ / 2; jp += 256) {
    float2 fv = ((const float2*)(fd + (size_t)bh * N_))[jp];
    E1p[jp] = pk2h(exp2f(fv.x * 1.44269504f), exp2f(fv.y * 1.44269504f));
    E2p[jp] = pk2h(exp2f(fv.x * 0.28853901f), exp2f(fv.y * 0.28853901f));
  }
  const int iA0 = i0 + wv * 32 + m16;
  const int iA1 = iA0 + 16;
  // R = e^{-0.8 fs} (row-scale-invariant form); clamp away f16 overflow
  const h2 R0 = h2splat(fminf(exp2f(fs[(size_t)bh * N_ + iA0] * -1.15415603f), 60000.f));
  const h2 R1 = h2splat(fminf(exp2f(fs[(size_t)bh * N_ + iA1] * -1.15415603f), 60000.f));
  const uint32_t* arow0 = adjp + ((size_t)b * N_ + iA0) * 32;
  const uint32_t* arow1 = adjp + ((size_t)b * N_ + iA1) * 32;
  union { uint16_t u[8]; f16x8 v; } ones;
#pragma unroll
  for (int e = 0; e < 8; e++) ones.u[e] = 0x3C00u;  // 1.0 f16
  f32x4 acc[2][5] = {};
  const int csw = (m16 & 7) << 3;                    // read-side XOR (elements)
  uint4 aw0 = *(const uint4*)(arow0);
  uint4 aw1 = *(const uint4*)(arow1);
  for (int c = 0; c < 8; c++) {
    __syncthreads();   // vmcnt drained -> Hs[c&1] staged; E ready (c=0);
                       // Hs[c^1] reads from chunk c-1 done (WAR for STAGE below)
    if (c < 7) STAGE((c + 1) * 128, Hs[(c + 1) & 1]);
    const uint32_t cw0[4] = {aw0.x, aw0.y, aw0.z, aw0.w};
    const uint32_t cw1[4] = {aw1.x, aw1.y, aw1.z, aw1.w};
    if (c < 7) {
      aw0 = *(const uint4*)(arow0 + (c + 1) * 4);
      aw1 = *(const uint4*)(arow1 + (c + 1) * 4);
    }
    const uint16_t* Hc = Hs[c & 1];
    const int eb = c * 64;
#pragma unroll
    for (int s = 0; s < 4; s++) {
      const int js = s * 32;
      const int jb = (js + q * 8) ^ csw;
      f16x8 hf0 = *(const f16x8*)&Hc[(m16)*128      + jb];
      f16x8 hf1 = *(const f16x8*)&Hc[(16 + m16)*128 + jb];
      f16x8 hf2 = *(const f16x8*)&Hc[(32 + m16)*128 + jb];
      f16x8 hf3 = *(const f16x8*)&Hc[(48 + m16)*128 + jb];
      const int ei = eb + s * 16 + q * 4;
      const uint4 e1u = *(const uint4*)&E1p[ei];
      const uint4 e2u = *(const uint4*)&E2p[ei];
      const h2 e1[4] = {u2h2(e1u.x), u2h2(e1u.y), u2h2(e1u.z), u2h2(e1u.w)};
      const h2 e2[4] = {u2h2(e2u.x), u2h2(e2u.y), u2h2(e2u.z), u2h2(e2u.w)};
      const uint32_t ab0 = (cw0[s] >> (q * 8)) & 0xffu;
      const uint32_t ab1 = (cw1[s] >> (q * 8)) & 0xffu;
      const uint32_t t0 = ab0 | (ab0 << 15);   // bit 2p @2p, bit 2p+1 @2p+16
      const uint32_t t1 = ab1 | (ab1 << 15);
#pragma unroll
      for (int f = 0; f < 2; f++) {
        const h2 Rf = f ? R1 : R0;
        const uint32_t tt = f ? t1 : t0;
        union { uint32_t u[4]; f16x8 v; } af;
#pragma unroll
        for (int p = 0; p < 4; p++) {
          h2 pm = hmax2(e1[p], Rf * e2[p]);
          af.u[p] = h22u(pm) & (((tt >> (2 * p)) & 0x10001u) * 0xFFFFu);
        }
        acc[f][0] = __builtin_amdgcn_mfma_f32_16x16x32_f16(af.v, hf0, acc[f][0], 0, 0, 0);
        acc[f][1] = __builtin_amdgcn_mfma_f32_16x16x32_f16(af.v, hf1, acc[f][1], 0, 0, 0);
        acc[f][2] = __builtin_amdgcn_mfma_f32_16x16x32_f16(af.v, hf2, acc[f][2], 0, 0, 0);
        acc[f][3] = __builtin_amdgcn_mfma_f32_16x16x32_f16(af.v, hf3, acc[f][3], 0, 0, 0);
        acc[f][4] = __builtin_amdgcn_mfma_f32_16x16x32_f16(af.v, ones.v, acc[f][4], 0, 0, 0);
      }
    }
  }
#undef STAGE
#pragma unroll
  for (int f = 0; f < 2; f++) {
    float linv[4];
#pragma unroll
    for (int r = 0; r < 4; r++) linv[r] = 1.0f / acc[f][4][r];
    const int ibl = i0 + wv * 32 + f * 16 + q * 4;
#pragma unroll
    for (int nt = 0; nt < 4; nt++)
#pragma unroll
      for (int r = 0; r < 4; r++) {
        oat[((size_t)b * N_ + ibl + r) * D_ + h * DH_ + nt * 16 + m16] =
            f2h(acc[f][nt][r] * linv[r]);
      }
  }
}

// ---------------- final: y = LN2(x + elu(oat)); output dtype matches input
__global__ __launch_bounds__(256) void k_final(const void* __restrict__ x,
                                               const uint16_t* __restrict__ oa,
                                               const void* __restrict__ g,
                                               const void* __restrict__ bb,
                                               void* __restrict__ out,
                                               const int* __restrict__ flag) {
  const int f32 = *flag;
  const int row = blockIdx.x * 4 + (threadIdx.x >> 6);
  const int lane = threadIdx.x & 63;
  const size_t base = (size_t)row * D_ + lane * 8;
  float xv[8]; load8f(x, base, f32, xv);
  uint4 av = *(const uint4*)(oa + base);
  const uint32_t* aw = (const uint32_t*)&av;
  float v[8], s = 0.f, sq = 0.f;
#pragma unroll
  for (int e = 0; e < 4; e++) {
    float a0 = h2f((uint16_t)(aw[e] & 0xffffu));
    float a1 = h2f((uint16_t)(aw[e] >> 16));
    a0 = a0 > 0.f ? a0 : exp2f(a0 * 1.44269504f) - 1.0f;
    a1 = a1 > 0.f ? a1 : exp2f(a1 * 1.44269504f) - 1.0f;
    float t0 = xv[2*e] + a0, t1 = xv[2*e+1] + a1;
    v[2*e] = t0; v[2*e+1] = t1;
    s += t0 + t1; sq += t0 * t0 + t1 * t1;
  }
#pragma unroll
  for (int d = 32; d; d >>= 1) { s += __shfl_xor(s, d); sq += __shfl_xor(sq, d); }
  const float mean = s * (1.0f / D_);
  float var = fmaxf(sq * (1.0f / D_) - mean * mean, 0.0f);
  const float inv = 1.0f / (sqrtf(var) + 1e-6f);
  float gv[8], bv[8];
  load8f(g, lane * 8, f32, gv); load8f(bb, lane * 8, f32, bv);
  float r8[8];
#pragma unroll
  for (int e = 0; e < 8; e++) r8[e] = gv[e] * ((v[e] - mean) * inv) + bv[e];
  if (f32) {
    float* o = (float*)out + base;
    float4 o0 = {r8[0], r8[1], r8[2], r8[3]};
    float4 o1 = {r8[4], r8[5], r8[6], r8[7]};
    *(float4*)(o) = o0;
    *(float4*)(o + 4) = o1;
  } else {
    uint4 ov; uint32_t* ow = (uint32_t*)&ov;
#pragma unroll
    for (int e = 0; e < 4; e++)
      ow[e] = (uint32_t)f2bf(r8[2*e]) | ((uint32_t)f2bf(r8[2*e+1]) << 16);
    *(uint4*)((uint16_t*)out + base) = ov;
  }
}

extern "C" void kernel_launch(void* const* d_in, const int* in_sizes, int n_in,
                              void* d_out, int out_size, void* d_ws, size_t ws_size,
                              hipStream_t stream) {
  const void* x = d_in[0];
  // d_in[1] = mask (unused)
  const int* adj = (const int*)d_in[2];
  const void* W = d_in[3];
  const void* asr = d_in[4];
  const void* adst = d_in[5];
  const void* g1 = d_in[6];
  const void* b1 = d_in[7];
  const void* g2 = d_in[8];
  const void* b2 = d_in[9];

  uint8_t* ws = (uint8_t*)d_ws;
  uint16_t* ht = (uint16_t*)(ws);                // 8 MB  [bh][dh][n] f16
  uint16_t* xn = (uint16_t*)(ws + 8388608);      // 8 MB  (reused as oat)
  uint16_t* oat = xn;
  uint16_t* Wt = (uint16_t*)(ws + 16777216);     // 512 KB
  uint32_t* adjp = (uint32_t*)(ws + 17301504);   // 1 MB
  float* fs = (float*)(ws + 18350080);           // 256 KB
  float* fd = (float*)(ws + 18612224);           // 256 KB
  int* flag = (int*)(ws + 18874368);             // 4 B dtype flag

  k_pp<<<dim3(4161), dim3(256), 0, stream>>>(adj, (unsigned long long*)adjp,
                                             (const uint16_t*)x, flag,
                                             x, g1, b1, xn, W, Wt);
  k_gemm<<<dim3(8, 128), dim3(256), 0, stream>>>(xn, Wt, ht, asr, adst, fs, fd, flag);
  k_attn<<<dim3(512), dim3(256), 0, stream>>>(ht, fs, fd, adjp, oat);
  k_final<<<dim3(2048), dim3(256), 0, stream>>>(x, oat, g2, b2, d_out, flag);
}